// Round 13
// baseline (221.641 us; speedup 1.0000x reference)
//
#include <hip/hip_runtime.h>
#include <hip/hip_fp16.h>

#define N_NODES    100000
#define N_EDGES    1600000
#define NUM_GRAPHS 64
#define F          64
#define EPS        1e-5f
#define DEG_CAP    64
#define NPART      8
#define PART_SZ    (N_NODES / NPART)          // 12500
#define BIN_CAP    262144                     // per-partition pair capacity (exp ~200K)
#define F2_PER     256                        // fill2 blocks per partition

typedef __attribute__((ext_vector_type(8))) _Float16 f16x8;
typedef __attribute__((ext_vector_type(4))) float    f32x4;

// ---------------- init: zero cnt / pooled / binCnt ----------------
__global__ void k_init(int* cnt, float* pooled, int* binCnt) {
    int i = blockIdx.x * blockDim.x + threadIdx.x;
    if (i < 3 * NUM_GRAPHS * F) pooled[i] = 0.f;
    if (i < N_NODES) cnt[i] = 0;
    if (i < NPART) binCnt[i] = 0;
}

// ---------------- phase 1: bin edges by dst partition (dense writes) ----------------
__global__ void k_bin(const int* __restrict__ src, const int* __restrict__ dst,
                      int* __restrict__ binCnt, int2* __restrict__ bins) {
    __shared__ int bcnt[NPART];
    __shared__ int bbase[NPART];
    int t = threadIdx.x;
    if (t < NPART) bcnt[t] = 0;
    __syncthreads();
    size_t e0 = (size_t)blockIdx.x * 1024 + (size_t)t * 4;   // N_EDGES % 4 == 0
    int4 dv = {0, 0, 0, 0}, sv = {0, 0, 0, 0};
    int p0 = 0, p1 = 0, p2 = 0, p3 = 0, r0 = 0, r1 = 0, r2 = 0, r3 = 0;
    bool valid = e0 < N_EDGES;
    if (valid) {
        dv = *(const int4*)(dst + e0);
        sv = *(const int4*)(src + e0);
        p0 = dv.x / PART_SZ; p1 = dv.y / PART_SZ;
        p2 = dv.z / PART_SZ; p3 = dv.w / PART_SZ;
        r0 = atomicAdd(&bcnt[p0], 1);              // LDS atomic: returns in-block rank
        r1 = atomicAdd(&bcnt[p1], 1);
        r2 = atomicAdd(&bcnt[p2], 1);
        r3 = atomicAdd(&bcnt[p3], 1);
    }
    __syncthreads();
    if (t < NPART) bbase[t] = atomicAdd(&binCnt[t], bcnt[t]);   // 8 global atomics/block
    __syncthreads();
    if (valid) {
        bins[(size_t)p0 * BIN_CAP + bbase[p0] + r0] = make_int2(sv.x, dv.x);
        bins[(size_t)p1 * BIN_CAP + bbase[p1] + r1] = make_int2(sv.y, dv.y);
        bins[(size_t)p2 * BIN_CAP + bbase[p2] + r2] = make_int2(sv.z, dv.z);
        bins[(size_t)p3 * BIN_CAP + bbase[p3] + r3] = make_int2(sv.w, dv.w);
    }
}

// ---------------- phase 2: partition-local scatter (XCD-L2-resident) ----------------
__global__ void k_fill2(const int* __restrict__ binCnt, const int2* __restrict__ bins,
                        int* __restrict__ cnt, int* __restrict__ bucket) {
    int p   = blockIdx.x & (NPART - 1);
    int sub = blockIdx.x >> 3;
    int n = binCnt[p]; if (n > BIN_CAP) n = BIN_CAP;
    const int2* bin = bins + (size_t)p * BIN_CAP;
    const int stride = F2_PER * 256;
    for (int i = sub * 256 + threadIdx.x; i < n; i += stride) {
        int2 e = bin[i];
        int slot = atomicAdd(&cnt[e.y], 1);        // L2-local atomic
        if (slot < DEG_CAP) bucket[(size_t)e.y * DEG_CAP + slot] = e.x;
    }
}

// ---------------- MFMA GEMM: hs[r] = fp16((h[r] @ W) * rsqrt(cnt[r]+1)) ----------------
#define N_TILES (N_NODES / 16)                 // 6250
#define GT_BLOCKS ((N_TILES + 3) / 4)          // 1563
__global__ void k_gemm_mfma(const float* __restrict__ h, const float* __restrict__ W,
                            const int* __restrict__ cnt, __half* __restrict__ out) {
    __shared__ _Float16 Wh[64 * 64];
    int t = threadIdx.x;
    for (int i = t; i < 64 * 64; i += 256) Wh[i] = (_Float16)W[i];
    __syncthreads();
    int lane = t & 63, wv = t >> 6;
    int tile = blockIdx.x * 4 + wv;
    if (tile >= N_TILES) return;
    int row0 = tile * 16;
    int r   = lane & 15;
    int g16 = lane >> 4;
    int k0  = g16 * 8;

    f16x8 Bf[4][2];
#pragma unroll
    for (int ct = 0; ct < 4; ++ct)
#pragma unroll
        for (int ck = 0; ck < 2; ++ck)
#pragma unroll
            for (int i = 0; i < 8; ++i)
                Bf[ct][ck][i] = Wh[(32 * ck + k0 + i) * 64 + ct * 16 + r];

    f16x8 Af[2];
#pragma unroll
    for (int ck = 0; ck < 2; ++ck) {
        const float4* x4 = (const float4*)(h + (size_t)(row0 + r) * F + 32 * ck + k0);
        float4 p = x4[0], q = x4[1];
        Af[ck][0] = (_Float16)p.x; Af[ck][1] = (_Float16)p.y;
        Af[ck][2] = (_Float16)p.z; Af[ck][3] = (_Float16)p.w;
        Af[ck][4] = (_Float16)q.x; Af[ck][5] = (_Float16)q.y;
        Af[ck][6] = (_Float16)q.z; Af[ck][7] = (_Float16)q.w;
    }

    f32x4 acc[4];
#pragma unroll
    for (int ct = 0; ct < 4; ++ct) {
        f32x4 z = {0.f, 0.f, 0.f, 0.f};
        acc[ct] = __builtin_amdgcn_mfma_f32_16x16x32_f16(Af[0], Bf[ct][0], z, 0, 0, 0);
        acc[ct] = __builtin_amdgcn_mfma_f32_16x16x32_f16(Af[1], Bf[ct][1], acc[ct], 0, 0, 0);
    }

#pragma unroll
    for (int j = 0; j < 4; ++j) {
        int rr = row0 + 4 * g16 + j;
        float di = rsqrtf((float)cnt[rr] + 1.0f);
#pragma unroll
        for (int ct = 0; ct < 4; ++ct)
            out[(size_t)rr * F + ct * 16 + r] = __float2half(acc[ct][j] * di);
    }
}

__device__ __forceinline__ float2 cvt2(unsigned int u) {
    __half2 h = *reinterpret_cast<__half2*>(&u);
    return __half22float2(h);
}

#define ACC8(u, wt)                                                          \
    {                                                                        \
        float2 p0 = cvt2((u).x), p1 = cvt2((u).y),                           \
               p2 = cvt2((u).z), p3 = cvt2((u).w);                           \
        a0 = fmaf(p0.x, wt, a0); a1 = fmaf(p0.y, wt, a1);                    \
        a2 = fmaf(p1.x, wt, a2); a3 = fmaf(p1.y, wt, a3);                    \
        a4 = fmaf(p2.x, wt, a4); a5 = fmaf(p2.y, wt, a5);                    \
        a6 = fmaf(p3.x, wt, a6); a7 = fmaf(p3.y, wt, a7);                    \
    }

#define RED8(D)                                                              \
    a0 += __shfl_xor(a0, D); a1 += __shfl_xor(a1, D);                        \
    a2 += __shfl_xor(a2, D); a3 += __shfl_xor(a3, D);                        \
    a4 += __shfl_xor(a4, D); a5 += __shfl_xor(a5, D);                        \
    a6 += __shfl_xor(a6, D); a7 += __shfl_xor(a7, D);

// ---------------- fused aggregate + bias + BN + ReLU + pooled reduce(s) ----------------
// 2 dst nodes per wave; 8 unconditional chunk loads in flight (fast path nent<=32).
template<bool WRITE_OUT, bool POOL_X>
__global__ void k_agg_pool(const __half* __restrict__ hs, const int* __restrict__ cnt,
                           const int* __restrict__ bucket,
                           const int* __restrict__ batch,
                           const float* __restrict__ x,
                           const float* __restrict__ b, const float* __restrict__ gamma,
                           const float* __restrict__ beta, const float* __restrict__ mean,
                           const float* __restrict__ var,
                           float* __restrict__ out,
                           float* __restrict__ pooledX, float* __restrict__ pooledV) {
    __shared__ float prowV[8][64];
    __shared__ float prowX[8][64];
    __shared__ int pg[8];
    int w    = threadIdx.x >> 6;
    int lane = threadIdx.x & 63;
    int half = lane & 31;
    int nsel = lane >> 5;
    int esub = half >> 3;
    int q    = half & 7;
    int base = lane & 32;
    int nodeIdx = w * 2 + nsel;
    int d = blockIdx.x * 8 + nodeIdx;          // 12500*8 == N_NODES exactly
    const uint4* hs4 = (const uint4*)hs;

    int cdeg = cnt[d];
    int kk = cdeg > (DEG_CAP - 1) ? (DEG_CAP - 1) : cdeg;
    int nent = kk + 1;
    int ev = d;
    if (half) ev = bucket[(size_t)d * DEG_CAP + half - 1];
    float2 xv = make_float2(0.f, 0.f);
    if (POOL_X) xv = ((const float2*)x)[(size_t)d * 32 + half];
    int g = batch[d];

    int t0 = 0  + esub, t1 = 4  + esub, t2 = 8  + esub, t3 = 12 + esub;
    int t4 = 16 + esub, t5 = 20 + esub, t6 = 24 + esub, t7 = 28 + esub;
    int s0 = __shfl(ev, base + (t0 < nent ? t0 : 0));
    int s1 = __shfl(ev, base + (t1 < nent ? t1 : 0));
    int s2 = __shfl(ev, base + (t2 < nent ? t2 : 0));
    int s3 = __shfl(ev, base + (t3 < nent ? t3 : 0));
    int s4 = __shfl(ev, base + (t4 < nent ? t4 : 0));
    int s5 = __shfl(ev, base + (t5 < nent ? t5 : 0));
    int s6 = __shfl(ev, base + (t6 < nent ? t6 : 0));
    int s7 = __shfl(ev, base + (t7 < nent ? t7 : 0));
    uint4 u0 = hs4[(size_t)s0 * 8 + q];
    uint4 u1 = hs4[(size_t)s1 * 8 + q];
    uint4 u2 = hs4[(size_t)s2 * 8 + q];
    uint4 u3 = hs4[(size_t)s3 * 8 + q];
    uint4 u4 = hs4[(size_t)s4 * 8 + q];
    uint4 u5 = hs4[(size_t)s5 * 8 + q];
    uint4 u6 = hs4[(size_t)s6 * 8 + q];
    uint4 u7 = hs4[(size_t)s7 * 8 + q];
    float a0 = 0.f, a1 = 0.f, a2 = 0.f, a3 = 0.f,
          a4 = 0.f, a5 = 0.f, a6 = 0.f, a7 = 0.f;
    { float wt = t0 < nent ? 1.f : 0.f; ACC8(u0, wt); }
    { float wt = t1 < nent ? 1.f : 0.f; ACC8(u1, wt); }
    { float wt = t2 < nent ? 1.f : 0.f; ACC8(u2, wt); }
    { float wt = t3 < nent ? 1.f : 0.f; ACC8(u3, wt); }
    { float wt = t4 < nent ? 1.f : 0.f; ACC8(u4, wt); }
    { float wt = t5 < nent ? 1.f : 0.f; ACC8(u5, wt); }
    { float wt = t6 < nent ? 1.f : 0.f; ACC8(u6, wt); }
    { float wt = t7 < nent ? 1.f : 0.f; ACC8(u7, wt); }

    if (__any(nent > 32)) {
        int evB = bucket[(size_t)d * DEG_CAP + 31 + half];
        evB = (evB < 0 || evB >= N_NODES) ? 0 : evB;
#pragma unroll
        for (int i = 0; i < 8; ++i) {
            int uu = 4 * i + esub;
            int tt = 32 + uu;
            int sB = __shfl(evB, base + uu);
            uint4 ub = hs4[(size_t)sB * 8 + q];
            float wt = tt < nent ? 1.f : 0.f;
            ACC8(ub, wt);
        }
    }

    RED8(8) RED8(16)
    float4 V0 = make_float4(0.f, 0.f, 0.f, 0.f);
    float4 V1 = make_float4(0.f, 0.f, 0.f, 0.f);
    if (half < 8) {
        float di = rsqrtf((float)cdeg + 1.0f);
        const float4* b4  = (const float4*)b;
        const float4* m4  = (const float4*)mean;
        const float4* v4  = (const float4*)var;
        const float4* g4  = (const float4*)gamma;
        const float4* e4  = (const float4*)beta;
        float4 bb0 = b4[2 * q], bb1 = b4[2 * q + 1];
        float4 mm0 = m4[2 * q], mm1 = m4[2 * q + 1];
        float4 vv0 = v4[2 * q], vv1 = v4[2 * q + 1];
        float4 gg0 = g4[2 * q], gg1 = g4[2 * q + 1];
        float4 ee0 = e4[2 * q], ee1 = e4[2 * q + 1];
        V0.x = fmaxf((di * a0 + bb0.x - mm0.x) * rsqrtf(vv0.x + EPS) * gg0.x + ee0.x, 0.f);
        V0.y = fmaxf((di * a1 + bb0.y - mm0.y) * rsqrtf(vv0.y + EPS) * gg0.y + ee0.y, 0.f);
        V0.z = fmaxf((di * a2 + bb0.z - mm0.z) * rsqrtf(vv0.z + EPS) * gg0.z + ee0.z, 0.f);
        V0.w = fmaxf((di * a3 + bb0.w - mm0.w) * rsqrtf(vv0.w + EPS) * gg0.w + ee0.w, 0.f);
        V1.x = fmaxf((di * a4 + bb1.x - mm1.x) * rsqrtf(vv1.x + EPS) * gg1.x + ee1.x, 0.f);
        V1.y = fmaxf((di * a5 + bb1.y - mm1.y) * rsqrtf(vv1.y + EPS) * gg1.y + ee1.y, 0.f);
        V1.z = fmaxf((di * a6 + bb1.z - mm1.z) * rsqrtf(vv1.z + EPS) * gg1.z + ee1.z, 0.f);
        V1.w = fmaxf((di * a7 + bb1.w - mm1.w) * rsqrtf(vv1.w + EPS) * gg1.w + ee1.w, 0.f);
        if (WRITE_OUT) {
            float4* o4 = (float4*)out;
            o4[(size_t)d * 16 + 2 * q]     = V0;
            o4[(size_t)d * 16 + 2 * q + 1] = V1;
        }
        float4* pv = (float4*)&prowV[nodeIdx][0];
        pv[2 * q]     = V0;
        pv[2 * q + 1] = V1;
    }
    if (POOL_X) {
        prowX[nodeIdx][2 * half]     = xv.x;
        prowX[nodeIdx][2 * half + 1] = xv.y;
    }
    if (half == 0) pg[nodeIdx] = g;
    __syncthreads();

    int f2 = threadIdx.x & 63;
    for (int r = threadIdx.x >> 6; r < 8; r += 4) {
        int gg = pg[r];
        bool first = true;
        for (int r2 = 0; r2 < r; ++r2) if (pg[r2] == gg) first = false;
        if (first) {
            float a = 0.f, bx = 0.f;
            for (int r2 = r; r2 < 8; ++r2)
                if (pg[r2] == gg) { a += prowV[r2][f2]; if (POOL_X) bx += prowX[r2][f2]; }
            atomicAdd(&pooledV[gg * F + f2], a);
            if (POOL_X) atomicAdd(&pooledX[gg * F + f2], bx);
        }
    }
}

// ---------------- head ----------------
__global__ void k_head(const float* __restrict__ pooled, const float* __restrict__ headW,
                       const float* __restrict__ headb, float* __restrict__ out) {
    int idx = blockIdx.x * blockDim.x + threadIdx.x;   // 1024 = 64*16
    if (idx >= NUM_GRAPHS * 16) return;
    int g = idx >> 4, o = idx & 15;
    float acc = 0.f;
#pragma unroll
    for (int l = 0; l < 3; ++l) {
        const float* pl = pooled + (size_t)l * NUM_GRAPHS * F + (size_t)g * F;
        const float* wl = headW + (size_t)l * F * 16;
        float s = 0.f;
        for (int k = 0; k < F; ++k) s += pl[k] * wl[k * 16 + o];
        acc += s + headb[l * 16 + o];
    }
    out[idx] = acc;
}

extern "C" void kernel_launch(void* const* d_in, const int* in_sizes, int n_in,
                              void* d_out, int out_size, void* d_ws, size_t ws_size,
                              hipStream_t stream) {
    const float* x     = (const float*)d_in[0];
    const int*   ei    = (const int*)d_in[1];
    const int*   src   = ei;
    const int*   dst   = ei + N_EDGES;
    const int*   batch = (const int*)d_in[2];
    const float* convW = (const float*)d_in[3];
    const float* convb = (const float*)d_in[4];
    const float* gamma = (const float*)d_in[5];
    const float* beta  = (const float*)d_in[6];
    const float* mean  = (const float*)d_in[7];
    const float* var   = (const float*)d_in[8];
    const float* headW = (const float*)d_in[9];
    const float* headb = (const float*)d_in[10];
    float* out = (float*)d_out;

    char* p = (char*)d_ws;
    int*    cnt    = (int*)p;       p += sizeof(int) * N_NODES;
    int*    bucket = (int*)p;       p += sizeof(int) * (size_t)N_NODES * DEG_CAP;
    __half* hs     = (__half*)p;    p += sizeof(__half) * (size_t)N_NODES * F;
    float*  hA     = (float*)p;     p += sizeof(float) * (size_t)N_NODES * F;
    float*  pooled = (float*)p;     p += sizeof(float) * 3 * NUM_GRAPHS * F;
    int*    binCnt = (int*)p;       p += sizeof(int) * NPART;
    int2*   bins   = (int2*)hA;     // alias: bins die before hA is first written

    const int B = 256;
    int gN   = (N_NODES + B - 1) / B;          // 391
    int gAgg = N_NODES / 8;                    // 12500 (2 nodes/wave, 8/block)
    int gBin = (N_EDGES + 1023) / 1024;        // 1563

    k_init <<<gN, B, 0, stream>>>(cnt, pooled, binCnt);
    k_bin  <<<gBin, B, 0, stream>>>(src, dst, binCnt, bins);
    k_fill2<<<NPART * F2_PER, B, 0, stream>>>(binCnt, bins, cnt, bucket);

    // ----- layer 0 (also pools x into rep0) -----
    k_gemm_mfma<<<GT_BLOCKS, B, 0, stream>>>(x, convW, cnt, hs);
    k_agg_pool<true, true><<<gAgg, B, 0, stream>>>(hs, cnt, bucket, batch, x, convb,
                                                   gamma, beta, mean, var,
                                                   hA, pooled, pooled + NUM_GRAPHS * F);

    // ----- layer 1 -----
    k_gemm_mfma<<<GT_BLOCKS, B, 0, stream>>>(hA, convW + F * F, cnt, hs);
    k_agg_pool<false, false><<<gAgg, B, 0, stream>>>(hs, cnt, bucket, batch, nullptr,
                                                     convb + F, gamma + F, beta + F,
                                                     mean + F, var + F,
                                                     nullptr, nullptr,
                                                     pooled + 2 * NUM_GRAPHS * F);

    // head
    k_head<<<(NUM_GRAPHS * 16 + B - 1) / B, B, 0, stream>>>(pooled, headW, headb, out);
}